// Round 10
// baseline (77.477 us; speedup 1.0000x reference)
//
#include <hip/hip_runtime.h>
#include <math.h>

#define BB 4
#define NN 512
#define DD 256
#define LL 64

#define WST1 257  // ODD row stride (words): read addr 257*l + d -> bank
                  // (l+d)%32, 64 lanes stride-1 through banks = 2 lanes/bank
                  // = FREE (m136).  Odd stride forbids b128 -> b32 reads, the
                  // exact pattern class m134 measured at 5.8 cyc.
#define IPB 4     // i-rows per k2 block: 512 blocks @ tiny LDS = 2 blocks/CU

// ---------------------------------------------------------------------------
// k1: xhatT[b][l][n] = lw[l] * sum_d x[b][n][d] * W[l][d]   ([l][n] layout --
// j fastest for k2's coalescing; lw>=0 so w|a-b| == |wa-wb|).
//
// ROUND-10 REDESIGN: every prior ~20us k1 used 8-address/8-lane-broadcast
// ds_read_b128 for BOTH operands (r4/r6/r7/r9 all ~20us across different
// block/barrier structures -> steady-state loop throughput, not occupancy).
// Theory: that broadcast pattern services ~4x slower than per-lane stride-1
// (model 5us vs measured 20us).  This version uses only measured-fast
// patterns in the loop:
//   - lane = l: reads W via per-lane-distinct stride-1-bank ds_read_b32;
//   - wave = n-row: x read as wave-uniform float4 VMEM (merged broadcast,
//     separate pipe, L2/L3-resident);
//   - 4 independent FMA chains (float4 acc).
// Staging: one-time 8-way-conflict b32 LDS writes (odd stride breaks f4
// alignment) ~1us; W re-read per block = 32MB aggregate L2/L3 ~1us.
// Block 256 thr (4 waves = 4 n-rows), grid 512, LDS 64.3KB -> 2 blocks/CU.
// ---------------------------------------------------------------------------
__global__ __launch_bounds__(256) void k1_proj(const float* __restrict__ x,
                                               const float* __restrict__ Wp,
                                               const float* __restrict__ lw,
                                               float* __restrict__ xhatT) {
  __shared__ float Wl[LL * WST1];       // 65,792 B
  const int bx   = blockIdx.x;
  const int b    = bx >> 7;             // grid = 4 b * 128 n-tiles
  const int n0   = (bx & 127) * 4;
  const int t    = threadIdx.x;
  const int wave = t >> 6;              // n-row within tile
  const int l    = t & 63;              // lane = feature row

  float wl = lw[l];                     // coalesced, consumed at the end

  // stage W: 4096 f4 / 256 thr = 16 iters, coalesced global reads; LDS
  // writes as 4 x b32 (odd stride): 8-way bank conflict, one-time cost.
  const float4* Wp4 = (const float4*)Wp;
  #pragma unroll
  for (int it = 0; it < 16; ++it) {
    int idx = it * 256 + t;
    int ll  = idx >> 6;                 // W row (wave-uniform)
    int dq  = idx & 63;
    float4 wv = Wp4[idx];
    float* dst = &Wl[ll * WST1 + dq * 4];
    dst[0] = wv.x; dst[1] = wv.y; dst[2] = wv.z; dst[3] = wv.w;
  }
  __syncthreads();

  // compute: one output per thread.  W: 256 ds_read_b32, bank-stride-1,
  // conflict-free.  x: 64 wave-uniform f4 VMEM loads (merged).
  const float*  wr  = &Wl[l * WST1];
  const float4* xr4 = (const float4*)(x + ((size_t)b * NN + n0 + wave) * DD);
  float4 a = make_float4(0.f, 0.f, 0.f, 0.f);
  #pragma unroll 8
  for (int dq = 0; dq < 64; ++dq) {
    float4 xv = xr4[dq];
    a.x += wr[dq * 4 + 0] * xv.x;
    a.y += wr[dq * 4 + 1] * xv.y;
    a.z += wr[dq * 4 + 2] * xv.z;
    a.w += wr[dq * 4 + 3] * xv.w;
  }
  // store: [l][n] -- lanes scatter at 2KB stride (1 dword/thread; ~1-2us
  // worst case across the kernel, accepted this round)
  xhatT[((size_t)b * LL + l) * NN + n0 + wave] =
      wl * ((a.x + a.y) + (a.z + a.w));
}

// ---------------------------------------------------------------------------
// k2: VERBATIM round-9 (best measured config, ~12-13us by subtraction).
// per (b, i-tile of IPB=4): dist -> leaky_relu -> rowmax -> adj*exp ->
// rowsum -> divide -> +1e-10.  512 threads, thread = column j.
// LDS = 256 B -> 512 blocks run 2/CU (16 waves) for latency hiding.
// ---------------------------------------------------------------------------
__global__ __launch_bounds__(512, 4) void k2_main(const float* __restrict__ xhatT,
                                                  const float* __restrict__ adj,
                                                  float* __restrict__ out) {
  __shared__ float redm[IPB * 8];
  __shared__ float reds[IPB * 8];

  const int bx   = blockIdx.x;
  const int b    = bx >> 7;             // NN/IPB == 128 tiles per batch
  const int i0   = (bx & 127) * IPB;
  const int t    = threadIdx.x;         // j
  const int wave = t >> 6;
  const int lane = t & 63;

  const float* xb = xhatT + (size_t)b * (LL * NN);

  // adj: the only HBM-cold read; issue all IPB upfront, hidden under l-loop
  const float* adjb = adj + ((size_t)b * NN + i0) * NN;
  float adjv[IPB];
  #pragma unroll
  for (int r = 0; r < IPB; ++r) adjv[r] = adjb[(size_t)r * NN + t];

  float acc[IPB] = {0.f, 0.f, 0.f, 0.f};
  #pragma unroll 16
  for (int l = 0; l < LL; ++l) {
    float  p  = xb[l * NN + t];                       // coalesced, L2
    float4 xi = *(const float4*)(xb + l * NN + i0);   // uniform -> merged
    acc[0] += fabsf(xi.x - p);
    acc[1] += fabsf(xi.y - p);
    acc[2] += fabsf(xi.z - p);
    acc[3] += fabsf(xi.w - p);
  }

  // leaky_relu (dist >= 0 in practice, but stay faithful)
  #pragma unroll
  for (int r = 0; r < IPB; ++r) {
    float d = acc[r];
    acc[r] = d >= 0.f ? d : 0.01f * d;
  }

  // row max over 512 j: wave shfl reduce, then cross-wave via LDS
  #pragma unroll
  for (int r = 0; r < IPB; ++r) {
    float m = acc[r];
    #pragma unroll
    for (int off = 32; off > 0; off >>= 1)
      m = fmaxf(m, __shfl_xor(m, off, 64));
    if (lane == 0) redm[r * 8 + wave] = m;
  }
  __syncthreads();

  float e[IPB];
  #pragma unroll
  for (int r = 0; r < IPB; ++r) {
    float m = redm[r * 8 + 0];
    #pragma unroll
    for (int k = 1; k < 8; ++k) m = fmaxf(m, redm[r * 8 + k]);
    e[r] = adjv[r] * __expf(acc[r] - m);
  }

  // row sum
  #pragma unroll
  for (int r = 0; r < IPB; ++r) {
    float s = e[r];
    #pragma unroll
    for (int off = 32; off > 0; off >>= 1)
      s += __shfl_xor(s, off, 64);
    if (lane == 0) reds[r * 8 + wave] = s;
  }
  __syncthreads();

  float* outb = out + ((size_t)b * NN + i0) * NN;
  #pragma unroll
  for (int r = 0; r < IPB; ++r) {
    float s = reds[r * 8 + 0];
    #pragma unroll
    for (int k = 1; k < 8; ++k) s += reds[r * 8 + k];
    outb[(size_t)r * NN + t] = e[r] / s + 1e-10f;     // epsilon AFTER division
  }
}

extern "C" void kernel_launch(void* const* d_in, const int* in_sizes, int n_in,
                              void* d_out, int out_size, void* d_ws, size_t ws_size,
                              hipStream_t stream) {
  const float* x   = (const float*)d_in[0];   // [B,N,D]
  const float* adj = (const float*)d_in[1];   // [B,N,N]
  const float* Wp  = (const float*)d_in[2];   // [L,D]
  const float* lw  = (const float*)d_in[3];   // [L]
  float* out   = (float*)d_out;               // [B,N,N]
  float* xhatT = (float*)d_ws;                // [B,L,N] = 512 KiB

  hipLaunchKernelGGL(k1_proj, dim3(BB * 2 * (NN / 8)), dim3(256), 0, stream,
                     x, Wp, lw, xhatT);
  hipLaunchKernelGGL(k2_main, dim3(BB * NN / IPB), dim3(512), 0, stream,
                     xhatT, adj, out);
}

// Round 11
// 75.172 us; speedup vs baseline: 1.0307x; 1.0307x over previous
//
#include <hip/hip_runtime.h>
#include <math.h>

#define BB 4
#define NN 512
#define DD 256
#define LL 64

#define WST 260  // 260 % 32 == 4: 8 consecutive rows' b128 chunks land on 8
                 // distinct 16-B bank slots -> broadcast reads conflict-free
#define IPB 4    // i-rows per k2 block: 512 blocks @ tiny LDS = 2 blocks/CU

// ---------------------------------------------------------------------------
// k1: xhat quad layout [b][l4=16][n=512][c=4], element (b,l,n) at
//     ((b*16 + l/4)*512 + n)*4 + (l%4),  value = lw[l] * dot(x[b][n], W[l]).
// (lw>=0 so w|a-b| == |wa-wb| -- folded as in all passing rounds.)
// Structure = round-9 k1 VERBATIM (equal-best measured) except the final
// store index.  Store coalescing: a wave covers 2 l-quads x 8 n -> two
// 128-B contiguous segments per store instruction.
// ---------------------------------------------------------------------------
__global__ __launch_bounds__(256) void k1_proj(const float* __restrict__ x,
                                               const float* __restrict__ Wp,
                                               const float* __restrict__ lw,
                                               float* __restrict__ xhat) {
  __shared__ __align__(16) float Wl[32 * WST];   // 33,280 B (W half)
  __shared__ __align__(16) float xs[8 * WST];    //  8,320 B
  const int bx = blockIdx.x;
  const int nt = bx & 63;               // n-tile (fastest: neighbors share W)
  const int lh = (bx >> 6) & 1;         // l-half
  const int b  = bx >> 7;
  const int n0 = nt * 8;
  const int t  = threadIdx.x;

  const int ll = t >> 3;                // 0..31: 8 distinct W rows per wave
  const int r  = t & 7;                 // 8 distinct x rows per wave

  float wl = lw[lh * 32 + ll];          // issue early, consumed at the end

  // stage W half: 2048 float4 / 256 threads = 8 iters; coalesced global,
  // conflict-free b128 LDS writes
  const float4* Wp4 = (const float4*)Wp + (size_t)lh * 32 * 64;
  #pragma unroll
  for (int it = 0; it < 8; ++it) {
    int idx = it * 256 + t;
    int lr  = idx >> 6;                 // 0..31 (wave-uniform)
    int dq  = idx & 63;
    *(float4*)&Wl[lr * WST + dq * 4] = Wp4[idx];
  }
  // stage 8 x rows: 512 float4 / 256 threads = 2 iters, coalesced
  {
    const float4* x4 = (const float4*)(x + ((size_t)b * NN + n0) * DD);
    #pragma unroll
    for (int it = 0; it < 2; ++it) {
      int idx = it * 256 + t;
      *(float4*)&xs[(idx >> 6) * WST + (idx & 63) * 4] = x4[idx];
    }
  }
  __syncthreads();

  const float4* wrow = (const float4*)&Wl[ll * WST];
  const float4* xrow = (const float4*)&xs[r * WST];
  float4 a = make_float4(0.f, 0.f, 0.f, 0.f);
  #pragma unroll 8
  for (int dd = 0; dd < 64; ++dd) {
    float4 wv = wrow[dd];               // 8 rows x 8-lane bcast, conflict-free
    float4 xv = xrow[dd];               // 8 rows x 8-lane bcast, conflict-free
    a.x += xv.x * wv.x;
    a.y += xv.y * wv.y;
    a.z += xv.z * wv.z;
    a.w += xv.w * wv.w;
  }
  // quad-interleaved store: [b][l>>2][n][l&3]
  const int l = lh * 32 + ll;
  xhat[(((size_t)b * 16 + (l >> 2)) * NN + n0 + r) * 4 + (l & 3)] =
      wl * ((a.x + a.y) + (a.z + a.w));
}

// ---------------------------------------------------------------------------
// k2: per (b, i-tile of IPB=4): dist -> leaky_relu -> rowmax -> adj*exp ->
//     rowsum -> divide -> +1e-10.  512 threads, thread = column j.
//
// ROUND-11 CHANGE: with the [l4][n][4] quad layout, thread j's xj load is
// one dwordx4 covering 4 l's, WAVE-COALESCED (64 lanes x 16 B consecutive).
// VMEM instrs/thread: 16 xj + 4 adj + 4 out = 24  (was ~132: 64 scalar
// dwords + 64 same-address f4).  xi tile (IPB rows x 64 l = 1 KB) staged in
// LDS, read as same-address b128 broadcasts (free).  #pragma unroll 4
// bounds live xj f4s to 4 (r1/r7 spill lesson).  Reductions verbatim r9.
// LDS ~1.3 KB -> 512 blocks run 2/CU (16 waves) for latency hiding.
// ---------------------------------------------------------------------------
__global__ __launch_bounds__(512, 4) void k2_main(const float* __restrict__ xhat,
                                                  const float* __restrict__ adj,
                                                  float* __restrict__ out) {
  __shared__ __align__(16) float4 xi_s[16 * IPB];  // [l4][r]
  __shared__ float redm[IPB * 8];
  __shared__ float reds[IPB * 8];

  const int bx   = blockIdx.x;
  const int b    = bx >> 7;             // NN/IPB == 128 tiles per batch
  const int i0   = (bx & 127) * IPB;
  const int t    = threadIdx.x;         // j
  const int wave = t >> 6;
  const int lane = t & 63;

  // xhat as float4 array: entry (l4, n) at xb4[l4*NN + n]
  const float4* xb4 = (const float4*)xhat + (size_t)b * 16 * NN;

  // adj: the only HBM-cold read; issue all IPB upfront, hidden under l-loop
  const float* adjb = adj + ((size_t)b * NN + i0) * NN;
  float adjv[IPB];
  #pragma unroll
  for (int r = 0; r < IPB; ++r) adjv[r] = adjb[(size_t)r * NN + t];

  // stage xi tile: 64 threads load one f4 each (scattered 16-B, L2)
  if (t < 16 * IPB) {
    int l4 = t >> 2, r = t & 3;
    xi_s[l4 * IPB + r] = xb4[l4 * NN + i0 + r];
  }
  __syncthreads();

  float acc[IPB] = {0.f, 0.f, 0.f, 0.f};
  #pragma unroll 4
  for (int l4 = 0; l4 < 16; ++l4) {
    float4 xj = xb4[l4 * NN + t];       // coalesced dwordx4: 4 l's at once
    #pragma unroll
    for (int r = 0; r < IPB; ++r) {
      float4 xi = xi_s[l4 * IPB + r];   // same-address broadcast b128
      acc[r] += fabsf(xi.x - xj.x) + fabsf(xi.y - xj.y) +
                fabsf(xi.z - xj.z) + fabsf(xi.w - xj.w);
    }
  }

  // leaky_relu (dist >= 0 in practice, but stay faithful)
  #pragma unroll
  for (int r = 0; r < IPB; ++r) {
    float d = acc[r];
    acc[r] = d >= 0.f ? d : 0.01f * d;
  }

  // row max over 512 j: wave shfl reduce, then cross-wave via LDS
  #pragma unroll
  for (int r = 0; r < IPB; ++r) {
    float m = acc[r];
    #pragma unroll
    for (int off = 32; off > 0; off >>= 1)
      m = fmaxf(m, __shfl_xor(m, off, 64));
    if (lane == 0) redm[r * 8 + wave] = m;
  }
  __syncthreads();

  float e[IPB];
  #pragma unroll
  for (int r = 0; r < IPB; ++r) {
    float m = redm[r * 8 + 0];
    #pragma unroll
    for (int k = 1; k < 8; ++k) m = fmaxf(m, redm[r * 8 + k]);
    e[r] = adjv[r] * __expf(acc[r] - m);
  }

  // row sum
  #pragma unroll
  for (int r = 0; r < IPB; ++r) {
    float s = e[r];
    #pragma unroll
    for (int off = 32; off > 0; off >>= 1)
      s += __shfl_xor(s, off, 64);
    if (lane == 0) reds[r * 8 + wave] = s;
  }
  __syncthreads();

  float* outb = out + ((size_t)b * NN + i0) * NN;
  #pragma unroll
  for (int r = 0; r < IPB; ++r) {
    float s = reds[r * 8 + 0];
    #pragma unroll
    for (int k = 1; k < 8; ++k) s += reds[r * 8 + k];
    outb[(size_t)r * NN + t] = e[r] / s + 1e-10f;     // epsilon AFTER division
  }
}

extern "C" void kernel_launch(void* const* d_in, const int* in_sizes, int n_in,
                              void* d_out, int out_size, void* d_ws, size_t ws_size,
                              hipStream_t stream) {
  const float* x   = (const float*)d_in[0];   // [B,N,D]
  const float* adj = (const float*)d_in[1];   // [B,N,N]
  const float* Wp  = (const float*)d_in[2];   // [L,D]
  const float* lw  = (const float*)d_in[3];   // [L]
  float* out  = (float*)d_out;                // [B,N,N]
  float* xhat = (float*)d_ws;                 // [B][16][512][4] = 512 KiB

  hipLaunchKernelGGL(k1_proj, dim3(BB * 2 * (NN / 8)), dim3(256), 0, stream,
                     x, Wp, lw, xhat);
  hipLaunchKernelGGL(k2_main, dim3(BB * NN / IPB), dim3(512), 0, stream,
                     xhat, adj, out);
}